// Round 6
// baseline (64.455 us; speedup 1.0000x reference)
//
#include <hip/hip_runtime.h>

#define DIMK 128

typedef __bf16 bf16x8 __attribute__((ext_vector_type(8)));
typedef float  f32x4  __attribute__((ext_vector_type(4)));

// ---- helpers ---------------------------------------------------------------
__device__ inline unsigned short f32_to_bf16_rne(float f) {
    unsigned u = __float_as_uint(f);
    u += 0x7FFFu + ((u >> 16) & 1u);      // round-to-nearest-even
    return (unsigned short)(u >> 16);
}

// Fragment-pack layout for a 16-row tile:
//   ushort offset = tile*2048 + kk*512 + (kb*16 + col)*8 + j
// for element [tile*16+col][kk*32 + kb*8 + j]; per-lane (lane = kb*16+col)
// a fragment load is  base + kk*512 + lane*8  -> 16B contiguous per lane.

// ---- kernel 1: pack fp32 rows -> scaled bf16 fragment tiles + row norms ----
__global__ void pack_rows(const float* __restrict__ src,
                          unsigned short* __restrict__ dst,
                          float* __restrict__ norm2,
                          int n_valid, int n_rows_pad, float scale) {
    int wave = threadIdx.x >> 6, lane = threadIdx.x & 63;
    int row = blockIdx.x * 4 + wave;
    if (row >= n_rows_pad) return;
    int srow = min(row, n_valid - 1);
    int e = lane * 2;
    float2 v = *(const float2*)(src + (size_t)srow * DIMK + e);
    unsigned pk = (unsigned)f32_to_bf16_rne(scale * v.x) |
                  ((unsigned)f32_to_bf16_rne(scale * v.y) << 16);
    int tile = row >> 4, col = row & 15;
    int kk = e >> 5, kb = (e >> 3) & 3, j = e & 7;
    size_t off = (size_t)tile * 2048 + kk * 512 + (kb * 16 + col) * 8 + j;
    *(unsigned*)(dst + off) = pk;           // j even -> dword aligned
    float s = v.x * v.x + v.y * v.y;        // norm from UNscaled values
#pragma unroll
    for (int o = 1; o < 64; o <<= 1) s += __shfl_xor(s, o, 64);
    if (lane == 0) norm2[row] = s;
}

// ---- kernel 2: segment counts -> per-position (t2, w) packed float2 --------
__global__ void seg_weights(const int* __restrict__ ids,
                            const int* __restrict__ nseg_p,
                            const float* __restrict__ t2,
                            float2* __restrict__ tw, int n_pos) {
    __shared__ int   cnt[256];
    __shared__ float w[256];
    int nseg = nseg_p[0];
    if (nseg > 256) nseg = 256;
    int t = threadIdx.x;
    if (t < nseg) cnt[t] = 0;
    __syncthreads();
    for (int p = t; p < n_pos; p += blockDim.x) atomicAdd(&cnt[ids[p]], 1);
    __syncthreads();
    if (t < nseg) w[t] = 1.0f / ((float)nseg * (float)max(cnt[t], 1));
    __syncthreads();
    for (int p = t; p < n_pos; p += blockDim.x) {
        float2 e; e.x = t2[p]; e.y = w[ids[p]];
        tw[p] = e;
    }
}

// ---- kernel 3: fused cross-GEMM (+norm fold) + sqrt + weighted reduce ------
// 4 waves/block, wave owns 32 nodes. Target tiles staged via global_load_lds
// into a 4-deep LDS ring; counted vmcnt(2) + raw s_barrier per tile (loads
// stay in flight across barriers). t2 (bf16 hi/lo) and w staged to LDS once
// in the prologue; accumulator d = t2 + p2 - 2*cross directly.
__global__ __launch_bounds__(256)
void l2dist_main(const unsigned short* __restrict__ pb,   // packed bf16 pred
                 const float* __restrict__ p2,
                 const unsigned short* __restrict__ tb,   // packed bf16(-2*t)
                 const float2* __restrict__ tw,
                 float* __restrict__ out,
                 int n_nodes, int tiles) {
    __shared__ __align__(16) unsigned short lbuf[4][2048];  // 4 x 4KB ring
    __shared__ unsigned ext_lds[512];   // per-position t2 as packed bf16 hi|lo
    __shared__ __align__(16) float w_lds[512];

    const int tid  = threadIdx.x;
    const int lane = tid & 63;
    const int wave = tid >> 6;
    const int col  = lane & 15;
    const int kb   = lane >> 4;
    const int n0   = blockIdx.x * 128 + wave * 32;
    const unsigned short ONE = 0x3F80;   // bf16 1.0

    // ---- B fragments (2 node groups) + B-ext {1,1,p2hi,p2lo} on kb==0 ----
    bf16x8 bfrag[2][4];
    bf16x8 bext[2];
    const unsigned short* bp = pb + ((size_t)(n0 >> 4)) * 2048 + (size_t)lane * 8;
#pragma unroll
    for (int g = 0; g < 2; ++g) {
#pragma unroll
        for (int kk = 0; kk < 4; ++kk)
            bfrag[g][kk] = *(const bf16x8*)(bp + g * 2048 + kk * 512);
        float p2v = p2[n0 + g * 16 + col];
        unsigned short ph = f32_to_bf16_rne(p2v);
        float phf = __uint_as_float((unsigned)ph << 16);
        unsigned short pl = f32_to_bf16_rne(p2v - phf);
        union { unsigned short s[8]; bf16x8 v; } ub{};
        if (kb == 0) { ub.s[0] = ONE; ub.s[1] = ONE; ub.s[2] = ph; ub.s[3] = pl; }
        bext[g] = ub.v;
    }

    const int pbase = blockIdx.y * tiles;

    // ---- prologue: fill t2-ext and w into LDS ----
    for (int i = tid; i < tiles * 16; i += 256) {
        float2 e = tw[pbase * 16 + i];
        unsigned short th = f32_to_bf16_rne(e.x);
        float thf = __uint_as_float((unsigned)th << 16);
        unsigned short tl = f32_to_bf16_rne(e.x - thf);
        ext_lds[i] = (unsigned)th | ((unsigned)tl << 16);
        w_lds[i] = e.y;
    }

    // ---- staging: each wave copies its 1KB quarter, linear lane order ----
    const unsigned short* sgp = tb + (size_t)pbase * 2048 + wave * 512 + lane * 8;
    unsigned short* ldst = &lbuf[0][0] + wave * 512;
#define STAGE(T)                                                                \
    __builtin_amdgcn_global_load_lds(                                          \
        (const __attribute__((address_space(1))) unsigned int*)(const void*)   \
            (sgp + (size_t)(T) * 2048),                                        \
        (__attribute__((address_space(3))) unsigned int*)(void*)               \
            (ldst + ((T) & 3) * 2048),                                         \
        16, 0, 0)

    STAGE(0);
    if (tiles > 1) STAGE(1);
    if (tiles > 2) STAGE(2);
    __syncthreads();   // one-time full drain: tiles 0-2 + ext/w published

    float acc0 = 0.f, acc1 = 0.f;

#define TILE_BODY(T, VMIMM)                                                     \
    {                                                                           \
        asm volatile("s_waitcnt vmcnt(" #VMIMM ")" ::: "memory");               \
        __builtin_amdgcn_s_barrier();                                           \
        __builtin_amdgcn_sched_barrier(0);                                      \
        const int t_ = (T);                                                     \
        if (t_ + 3 < tiles) { STAGE(t_ + 3); }                                  \
        const unsigned short* rb = &lbuf[0][0] + (t_ & 3) * 2048 + lane * 8;    \
        bf16x8 a0 = *(const bf16x8*)(rb);                                       \
        bf16x8 a1 = *(const bf16x8*)(rb + 512);                                 \
        bf16x8 a2 = *(const bf16x8*)(rb + 1024);                                \
        bf16x8 a3 = *(const bf16x8*)(rb + 1536);                                \
        union { unsigned short s[8]; bf16x8 v; } ua{};                          \
        if (kb == 0) {                                                          \
            unsigned uu = ext_lds[t_ * 16 + col];                               \
            ua.s[0] = (unsigned short)uu;                                       \
            ua.s[1] = (unsigned short)(uu >> 16);                               \
            ua.s[2] = ONE; ua.s[3] = ONE;                                       \
        }                                                                       \
        f32x4 wv = *(const f32x4*)&w_lds[t_ * 16 + kb * 4];                     \
        f32x4 d0 = {0.f, 0.f, 0.f, 0.f};                                        \
        f32x4 d1 = {0.f, 0.f, 0.f, 0.f};                                        \
        d0 = __builtin_amdgcn_mfma_f32_16x16x32_bf16(a0, bfrag[0][0], d0,0,0,0);\
        d1 = __builtin_amdgcn_mfma_f32_16x16x32_bf16(a0, bfrag[1][0], d1,0,0,0);\
        d0 = __builtin_amdgcn_mfma_f32_16x16x32_bf16(a1, bfrag[0][1], d0,0,0,0);\
        d1 = __builtin_amdgcn_mfma_f32_16x16x32_bf16(a1, bfrag[1][1], d1,0,0,0);\
        d0 = __builtin_amdgcn_mfma_f32_16x16x32_bf16(a2, bfrag[0][2], d0,0,0,0);\
        d1 = __builtin_amdgcn_mfma_f32_16x16x32_bf16(a2, bfrag[1][2], d1,0,0,0);\
        d0 = __builtin_amdgcn_mfma_f32_16x16x32_bf16(a3, bfrag[0][3], d0,0,0,0);\
        d1 = __builtin_amdgcn_mfma_f32_16x16x32_bf16(a3, bfrag[1][3], d1,0,0,0);\
        d0 = __builtin_amdgcn_mfma_f32_16x16x32_bf16(ua.v, bext[0],   d0,0,0,0);\
        d1 = __builtin_amdgcn_mfma_f32_16x16x32_bf16(ua.v, bext[1],   d1,0,0,0);\
        _Pragma("unroll")                                                       \
        for (int j = 0; j < 4; ++j) {                                           \
            acc0 = fmaf(wv[j], __builtin_amdgcn_sqrtf(fmaxf(d0[j], 0.f)), acc0);\
            acc1 = fmaf(wv[j], __builtin_amdgcn_sqrtf(fmaxf(d1[j], 0.f)), acc1);\
        }                                                                       \
    }

    // steady state: stage(t), t+1, t+2 may be in flight -> wait until <=2
    for (int t = 0; t < tiles - 2; ++t) TILE_BODY(t, 2);
    if (tiles >= 2) TILE_BODY(tiles - 2, 1);
    TILE_BODY(tiles - 1, 0);
#undef TILE_BODY
#undef STAGE

    // reduce over the 4 kb lane-groups -> per-node totals
    acc0 += __shfl_xor(acc0, 16, 64);
    acc0 += __shfl_xor(acc0, 32, 64);
    acc1 += __shfl_xor(acc1, 16, 64);
    acc1 += __shfl_xor(acc1, 32, 64);
    if (lane < 16) {
        int na = n0 + col;
        int nb = n0 + 16 + col;
        if (na < n_nodes) atomicAdd(out + na, acc0);
        if (nb < n_nodes) atomicAdd(out + nb, acc1);
    }
}

// ---- launcher --------------------------------------------------------------
extern "C" void kernel_launch(void* const* d_in, const int* in_sizes, int n_in,
                              void* d_out, int out_size, void* d_ws, size_t ws_size,
                              hipStream_t stream) {
    const float* pred  = (const float*)d_in[0];
    const float* tgt   = (const float*)d_in[1];
    const int*   ids   = (const int*)d_in[2];
    const int*   nsegp = (const int*)d_in[3];
    float* out = (float*)d_out;

    int n_nodes = in_sizes[0] / DIMK;
    int n_pos   = in_sizes[2];

    int gx = (n_nodes + 127) / 128;          // node blocks (128 nodes each)
    int n_rows_pad = gx * 128;               // pad pred tiles to grid coverage

    char* ws = (char*)d_ws;
    size_t off_pb = 0;                                        // packed pred bf16
    size_t off_tb = off_pb + (size_t)n_rows_pad * DIMK * 2;   // packed -2*target
    size_t off_p2 = off_tb + (size_t)n_pos * DIMK * 2;        // pred norms
    size_t off_t2 = off_p2 + (size_t)n_rows_pad * 4;          // target norms
    size_t off_tw = off_t2 + (size_t)n_pos * 4;               // (t2, w) pairs
    unsigned short* pb = (unsigned short*)(ws + off_pb);
    unsigned short* tb = (unsigned short*)(ws + off_tb);
    float*          p2 = (float*)(ws + off_p2);
    float*          t2 = (float*)(ws + off_t2);
    float2*         tw = (float2*)(ws + off_tw);

    pack_rows<<<(n_rows_pad + 3) / 4, 256, 0, stream>>>(pred, pb, p2, n_nodes, n_rows_pad, 1.0f);
    pack_rows<<<(n_pos + 3) / 4, 256, 0, stream>>>(tgt, tb, t2, n_pos, n_pos, -2.0f);
    seg_weights<<<1, 1024, 0, stream>>>(ids, nsegp, t2, tw, n_pos);
    hipMemsetAsync(out, 0, (size_t)out_size * sizeof(float), stream);

    const int YS = 8;                        // 128 position-tiles % 8 == 0
    int tiles = (n_pos >> 4) / YS;           // 16 for n_pos = 2048
    dim3 grid(gx, YS);
    l2dist_main<<<grid, 256, 0, stream>>>(pb, p2, tb, tw, out, n_nodes, tiles);
}

// Round 7
// 58.940 us; speedup vs baseline: 1.0936x; 1.0936x over previous
//
#include <hip/hip_runtime.h>

#define DIMK 128

typedef __bf16 bf16x8 __attribute__((ext_vector_type(8)));
typedef float  f32x4  __attribute__((ext_vector_type(4)));

// ---- helpers ---------------------------------------------------------------
__device__ inline unsigned short f32_to_bf16_rne(float f) {
    unsigned u = __float_as_uint(f);
    u += 0x7FFFu + ((u >> 16) & 1u);      // round-to-nearest-even
    return (unsigned short)(u >> 16);
}

// Fragment-pack layout for a 16-row tile:
//   ushort offset = tile*2048 + kk*512 + (kb*16 + col)*8 + j
// for element [tile*16+col][kk*32 + kb*8 + j]; per-lane (lane = kb*16+col)
// a fragment load is  base + kk*512 + lane*8  -> 16B contiguous per lane.

// ---- kernel 1: pack fp32 rows -> scaled bf16 fragment tiles + row norms ----
__global__ void pack_rows(const float* __restrict__ src,
                          unsigned short* __restrict__ dst,
                          float* __restrict__ norm2,
                          int n_valid, int n_rows_pad, float scale) {
    int wave = threadIdx.x >> 6, lane = threadIdx.x & 63;
    int row = blockIdx.x * 4 + wave;
    if (row >= n_rows_pad) return;
    int srow = min(row, n_valid - 1);
    int e = lane * 2;
    float2 v = *(const float2*)(src + (size_t)srow * DIMK + e);
    unsigned pk = (unsigned)f32_to_bf16_rne(scale * v.x) |
                  ((unsigned)f32_to_bf16_rne(scale * v.y) << 16);
    int tile = row >> 4, col = row & 15;
    int kk = e >> 5, kb = (e >> 3) & 3, j = e & 7;
    size_t off = (size_t)tile * 2048 + kk * 512 + (kb * 16 + col) * 8 + j;
    *(unsigned*)(dst + off) = pk;           // j even -> dword aligned
    float s = v.x * v.x + v.y * v.y;        // norms from UNscaled values
#pragma unroll
    for (int o = 1; o < 64; o <<= 1) s += __shfl_xor(s, o, 64);
    if (lane == 0) norm2[row] = s;
}

// ---- kernel 2: segment counts -> per-position (t2, w) packed float2 --------
__global__ void seg_weights(const int* __restrict__ ids,
                            const int* __restrict__ nseg_p,
                            const float* __restrict__ t2,
                            float2* __restrict__ tw, int n_pos) {
    __shared__ int   cnt[256];
    __shared__ float w[256];
    int nseg = nseg_p[0];
    if (nseg > 256) nseg = 256;
    int t = threadIdx.x;
    if (t < nseg) cnt[t] = 0;
    __syncthreads();
    for (int p = t; p < n_pos; p += blockDim.x) atomicAdd(&cnt[ids[p]], 1);
    __syncthreads();
    if (t < nseg) w[t] = 1.0f / ((float)nseg * (float)max(cnt[t], 1));
    __syncthreads();
    for (int p = t; p < n_pos; p += blockDim.x) {
        float2 e; e.x = t2[p]; e.y = w[ids[p]];
        tw[p] = e;
    }
}

// ---- kernel 3: fused cross-GEMM + sqrt + weighted reduce -------------------
// 4 waves/block, wave owns 32 nodes. Each block stages its WHOLE 8-tile
// position slice (32 KB) into LDS via global_load_lds in the prologue, syncs
// ONCE, then runs a fully-unrolled barrier-free compute loop (LDS is
// read-only after the sync). Target packed with scale -2 so s = d + t2 + p2.
#define SLICE_TILES 8
__global__ __launch_bounds__(256, 4)
void l2dist_main(const unsigned short* __restrict__ pb,   // packed bf16 pred
                 const float* __restrict__ p2,
                 const unsigned short* __restrict__ tb,   // packed bf16(-2*t)
                 const float2* __restrict__ tw,
                 float* __restrict__ out,
                 int n_nodes) {
    __shared__ __align__(16) unsigned short lbuf[SLICE_TILES][2048];  // 32 KB
    __shared__ __align__(16) float tw_lds[SLICE_TILES * 32];          // t2,w pairs

    const int tid  = threadIdx.x;
    const int lane = tid & 63;
    const int wave = tid >> 6;
    const int col  = lane & 15;
    const int kb   = lane >> 4;
    const int n0   = blockIdx.x * 128 + wave * 32;

    // B fragments: two node groups from packed pred + norms.
    bf16x8 bfrag[2][4];
    float p2g[2];
    const unsigned short* bp = pb + ((size_t)(n0 >> 4)) * 2048 + (size_t)lane * 8;
#pragma unroll
    for (int g = 0; g < 2; ++g) {
#pragma unroll
        for (int kk = 0; kk < 4; ++kk)
            bfrag[g][kk] = *(const bf16x8*)(bp + g * 2048 + kk * 512);
        p2g[g] = p2[n0 + g * 16 + col];
    }

    const int pbase = blockIdx.y * SLICE_TILES;     // first tile of this slice

    // tw -> LDS (one pass, 128 positions per slice)
    if (tid < SLICE_TILES * 16) {
        float2 e = tw[pbase * 16 + tid];
        tw_lds[2 * tid]     = e.x;
        tw_lds[2 * tid + 1] = e.y;
    }

    // stage all 8 tiles; each wave copies its 1KB quarter (linear lane order)
    const unsigned short* sgp = tb + (size_t)pbase * 2048 + wave * 512 + lane * 8;
    unsigned short* ldst = &lbuf[0][0] + wave * 512;
#pragma unroll
    for (int t = 0; t < SLICE_TILES; ++t) {
        __builtin_amdgcn_global_load_lds(
            (const __attribute__((address_space(1))) unsigned int*)(const void*)
                (sgp + (size_t)t * 2048),
            (__attribute__((address_space(3))) unsigned int*)(void*)
                (ldst + t * 2048),
            16, 0, 0);
    }
    __syncthreads();    // drains vmcnt+lgkm; LDS read-only afterwards

    float acc0 = 0.f, acc1 = 0.f;
#pragma unroll
    for (int t = 0; t < SLICE_TILES; ++t) {
        const unsigned short* rb = &lbuf[t][lane * 8];
        bf16x8 a0 = *(const bf16x8*)(rb);
        bf16x8 a1 = *(const bf16x8*)(rb + 512);
        bf16x8 a2 = *(const bf16x8*)(rb + 1024);
        bf16x8 a3 = *(const bf16x8*)(rb + 1536);

        f32x4 d0 = {0.f, 0.f, 0.f, 0.f};
        f32x4 d1 = {0.f, 0.f, 0.f, 0.f};
        d0 = __builtin_amdgcn_mfma_f32_16x16x32_bf16(a0, bfrag[0][0], d0, 0, 0, 0);
        d1 = __builtin_amdgcn_mfma_f32_16x16x32_bf16(a0, bfrag[1][0], d1, 0, 0, 0);
        d0 = __builtin_amdgcn_mfma_f32_16x16x32_bf16(a1, bfrag[0][1], d0, 0, 0, 0);
        d1 = __builtin_amdgcn_mfma_f32_16x16x32_bf16(a1, bfrag[1][1], d1, 0, 0, 0);
        d0 = __builtin_amdgcn_mfma_f32_16x16x32_bf16(a2, bfrag[0][2], d0, 0, 0, 0);
        d1 = __builtin_amdgcn_mfma_f32_16x16x32_bf16(a2, bfrag[1][2], d1, 0, 0, 0);
        d0 = __builtin_amdgcn_mfma_f32_16x16x32_bf16(a3, bfrag[0][3], d0, 0, 0, 0);
        d1 = __builtin_amdgcn_mfma_f32_16x16x32_bf16(a3, bfrag[1][3], d1, 0, 0, 0);

        // lane's 4 accumulator rows: tile-local kb*4 + {0..3}
        f32x4 w0 = *(const f32x4*)&tw_lds[(t * 16 + kb * 4) * 2];
        f32x4 w1 = *(const f32x4*)&tw_lds[(t * 16 + kb * 4) * 2 + 4];
        float t2v[4] = {w0[0], w0[2], w1[0], w1[2]};
        float wv[4]  = {w0[1], w0[3], w1[1], w1[3]};
#pragma unroll
        for (int j = 0; j < 4; ++j) {
            float s0 = d0[j] + (t2v[j] + p2g[0]);   // d = -2*cross
            float s1 = d1[j] + (t2v[j] + p2g[1]);
            acc0 = fmaf(wv[j], __builtin_amdgcn_sqrtf(fmaxf(s0, 0.f)), acc0);
            acc1 = fmaf(wv[j], __builtin_amdgcn_sqrtf(fmaxf(s1, 0.f)), acc1);
        }
    }

    // reduce over the 4 kb lane-groups -> per-node totals
    acc0 += __shfl_xor(acc0, 16, 64);
    acc0 += __shfl_xor(acc0, 32, 64);
    acc1 += __shfl_xor(acc1, 16, 64);
    acc1 += __shfl_xor(acc1, 32, 64);
    if (lane < 16) {
        int na = n0 + col;
        int nb = n0 + 16 + col;
        if (na < n_nodes) atomicAdd(out + na, acc0);
        if (nb < n_nodes) atomicAdd(out + nb, acc1);
    }
}

// ---- launcher --------------------------------------------------------------
extern "C" void kernel_launch(void* const* d_in, const int* in_sizes, int n_in,
                              void* d_out, int out_size, void* d_ws, size_t ws_size,
                              hipStream_t stream) {
    const float* pred  = (const float*)d_in[0];
    const float* tgt   = (const float*)d_in[1];
    const int*   ids   = (const int*)d_in[2];
    const int*   nsegp = (const int*)d_in[3];
    float* out = (float*)d_out;

    int n_nodes = in_sizes[0] / DIMK;
    int n_pos   = in_sizes[2];

    int gx = (n_nodes + 127) / 128;          // node blocks (128 nodes each)
    int n_rows_pad = gx * 128;               // pad pred tiles to grid coverage

    char* ws = (char*)d_ws;
    size_t off_pb = 0;                                        // packed pred bf16
    size_t off_tb = off_pb + (size_t)n_rows_pad * DIMK * 2;   // packed -2*target
    size_t off_p2 = off_tb + (size_t)n_pos * DIMK * 2;        // pred norms
    size_t off_t2 = off_p2 + (size_t)n_rows_pad * 4;          // target norms
    size_t off_tw = off_t2 + (size_t)n_pos * 4;               // (t2, w) pairs
    unsigned short* pb = (unsigned short*)(ws + off_pb);
    unsigned short* tb = (unsigned short*)(ws + off_tb);
    float*          p2 = (float*)(ws + off_p2);
    float*          t2 = (float*)(ws + off_t2);
    float2*         tw = (float2*)(ws + off_tw);

    pack_rows<<<(n_rows_pad + 3) / 4, 256, 0, stream>>>(pred, pb, p2, n_nodes, n_rows_pad, 1.0f);
    pack_rows<<<(n_pos + 3) / 4, 256, 0, stream>>>(tgt, tb, t2, n_pos, n_pos, -2.0f);
    seg_weights<<<1, 1024, 0, stream>>>(ids, nsegp, t2, tw, n_pos);
    hipMemsetAsync(out, 0, (size_t)out_size * sizeof(float), stream);

    int ys = (n_pos >> 4) / SLICE_TILES;     // 16 slices for n_pos = 2048
    dim3 grid(gx, ys);
    l2dist_main<<<grid, 256, 0, stream>>>(pb, p2, tb, tw, out, n_nodes);
}